// Round 1
// baseline (691.263 us; speedup 1.0000x reference)
//
#include <hip/hip_runtime.h>
#include <stdint.h>

typedef unsigned long long u64;
typedef unsigned int u32;

#define N_ANCH   36864
#define PRE_NMS_N 6000
#define POST_NMS_N 300
#define NBINS    8192
#define CAP      8192      // compacted-candidate capacity (power of 2 for bitonic)
#define NWORDS   94        // ceil(6016/64): 6000 bits rounded up to 64-multiple

// ---- workspace layout (bytes) ----
// 0        : float4 bbox[36864]    589824
// 589824   : u64    keys[36864]    294912
// 884736   : u64    ckeys[8192]     65536
// 950272   : float4 sboxes[6000]    96000
// 1046272  : u32    meta[4]         {counter, binB, count_less, pad}

__device__ __forceinline__ u64 make_key(float s, u32 idx) {
    u32 u = __float_as_uint(s);
    // ascending-sortable transform for float
    u32 sortable = u ^ ((u >> 31) ? 0xFFFFFFFFu : 0x80000000u);
    u32 hi = ~sortable;            // ascending key == descending score
    return ((u64)hi << 32) | (u64)idx;  // tie-break: ascending index (stable argsort)
}

// K1: decode + clip + valid + key build; also prefill ckeys pad and zero meta counter
__global__ void k_decode(const float4* __restrict__ anchors,
                         const float* __restrict__ cls,
                         const float4* __restrict__ reg,
                         const int* __restrict__ img_w,
                         const int* __restrict__ img_h,
                         float4* __restrict__ bbox,
                         u64* __restrict__ keys,
                         u64* __restrict__ ckeys,
                         u32* __restrict__ meta) {
    int i = blockIdx.x * blockDim.x + threadIdx.x;
    if (i == 0) meta[0] = 0u;
    if (i < CAP) ckeys[i] = ~0ull;      // pad for bitonic sort
    if (i >= N_ANCH) return;

    float4 a = anchors[i];
    float4 r = reg[i];
    float w  = a.z - a.x, h = a.w - a.y;
    float cx = a.x + 0.5f * w, cy = a.y + 0.5f * h;
    float pcx = r.x * w + cx, pcy = r.y * h + cy;
    float pw = expf(r.z) * w,  ph = expf(r.w) * h;
    float b0 = pcx - 0.5f * pw, b1 = pcy - 0.5f * ph;
    float b2 = pcx + 0.5f * pw, b3 = pcy + 0.5f * ph;

    float fh = (float)img_h[0], fw = (float)img_w[0];
    // reference: cols 0,2 clipped to [0, img_h]; cols 1,3 to [0, img_w]
    b0 = fminf(fmaxf(b0, 0.0f), fh);
    b2 = fminf(fmaxf(b2, 0.0f), fh);
    b1 = fminf(fmaxf(b1, 0.0f), fw);
    b3 = fminf(fmaxf(b3, 0.0f), fw);

    bool valid = (b2 - b0 >= 16.0f) && (b3 - b1 >= 16.0f);
    float score = valid ? cls[i] : -1e9f;

    bbox[i] = make_float4(b0, b1, b2, b3);
    keys[i] = make_key(score, (u32)i);
}

// K2: 13-bit-prefix histogram over keys; find boundary bin B such that
// count(bin < B) < 6000 <= count(bin <= B). One workgroup.
__global__ void k_select(const u64* __restrict__ keys, u32* __restrict__ meta) {
    __shared__ u32 hist[NBINS];
    __shared__ u32 psum[1024];
    int tid = threadIdx.x;
    for (int b = tid; b < NBINS; b += 1024) hist[b] = 0u;
    __syncthreads();
    for (int i = tid; i < N_ANCH; i += 1024)
        atomicAdd(&hist[(u32)(keys[i] >> 51)], 1u);
    __syncthreads();
    u32 s = 0;
    int base = tid * 8;
#pragma unroll
    for (int b = 0; b < 8; ++b) s += hist[base + b];
    psum[tid] = s;
    __syncthreads();
    for (int off = 1; off < 1024; off <<= 1) {
        u32 v = (tid >= off) ? psum[tid - off] : 0u;
        __syncthreads();
        psum[tid] += v;
        __syncthreads();
    }
    u32 incl = psum[tid];
    u32 excl = incl - s;
    if (excl < (u32)PRE_NMS_N && incl >= (u32)PRE_NMS_N) {
        u32 c = excl;
        for (int b = 0; b < 8; ++b) {
            u32 hv = hist[base + b];
            if (c + hv >= (u32)PRE_NMS_N) { meta[1] = (u32)(base + b); meta[2] = c; break; }
            c += hv;
        }
    }
}

// K3: compact all keys with bin <= B into ckeys (unordered; sort fixes order)
__global__ void k_compact(const u64* __restrict__ keys,
                          u64* __restrict__ ckeys,
                          u32* __restrict__ meta) {
    int i = blockIdx.x * blockDim.x + threadIdx.x;
    if (i >= N_ANCH) return;
    u32 B = meta[1];
    u64 k = keys[i];
    if ((u32)(k >> 51) <= B) {
        u32 pos = atomicAdd(&meta[0], 1u);
        if (pos < CAP) ckeys[pos] = k;
    }
}

// K4: single-workgroup bitonic sort of 8192 keys in LDS; gather top-6000 boxes
__global__ void k_sort(const u64* __restrict__ ckeys,
                       const float4* __restrict__ bbox,
                       float4* __restrict__ sboxes) {
    __shared__ u64 sk[CAP];   // 64 KiB
    int tid = threadIdx.x;
    for (int i = tid; i < CAP; i += 1024) sk[i] = ckeys[i];
    __syncthreads();
    for (int k = 2; k <= CAP; k <<= 1) {
        for (int j = k >> 1; j > 0; j >>= 1) {
            for (int idx = tid; idx < CAP; idx += 1024) {
                int p = idx ^ j;
                if (p > idx) {
                    u64 A = sk[idx], B = sk[p];
                    bool up = ((idx & k) == 0);
                    if ((A > B) == up) { sk[idx] = B; sk[p] = A; }
                }
            }
            __syncthreads();
        }
    }
    for (int r = tid; r < PRE_NMS_N; r += 1024) {
        u32 idx = (u32)sk[r];
        sboxes[r] = bbox[idx];
    }
}

// K5: greedy NMS over score-sorted boxes with exact early exit at 300 kept;
// writes the 300x4 output directly.
__global__ void k_nms(const float4* __restrict__ sboxes, float* __restrict__ out) {
    __shared__ float4 boxes[PRE_NMS_N];   // 96000 B
    __shared__ u64 removed[NWORDS];
    __shared__ int kept[POST_NMS_N];
    int tid = threadIdx.x;
    int lane = tid & 63, wave = tid >> 6;

    for (int r = tid; r < PRE_NMS_N; r += 1024) boxes[r] = sboxes[r];
    __syncthreads();

    // init removed mask: invalid boxes (and pad bits >= 6000) start removed
    for (int r = tid; r < NWORDS * 64; r += 1024) {
        bool rm = true;
        if (r < PRE_NMS_N) {
            float4 b = boxes[r];
            rm = !((b.z - b.x >= 16.0f) && (b.w - b.y >= 16.0f));
        }
        u64 m = __ballot(rm);
        if (lane == 0) removed[r >> 6] = m;
    }
    __syncthreads();

    int kc = 0;
    int i = 0;
    while (i < PRE_NMS_N) {
        // find next alive index >= i (all threads redundantly; same LDS -> same result)
        int w = i >> 6;
        u64 wd = removed[w] | ((1ull << (i & 63)) - 1ull);
        while (wd == ~0ull) {
            ++w;
            if (w >= NWORDS) break;
            wd = removed[w];
        }
        if (w >= NWORDS) break;
        i = (w << 6) + (__ffsll((u64)(~wd)) - 1);
        if (i >= PRE_NMS_N) break;

        if (tid == 0) kept[kc] = i;
        ++kc;
        if (kc >= POST_NMS_N) break;   // exact early exit: output needs first 300 kept only

        // suppress j > i with IoU > 0.7: each wave owns 64-aligned chunks
        float4 bi = boxes[i];
        float area_i = (bi.z - bi.x) * (bi.w - bi.y);
        for (int c = (i >> 6) + wave; c < NWORDS; c += 16) {
            int j = (c << 6) + lane;
            bool sup = false;
            if (j > i && j < PRE_NMS_N) {
                float4 bj = boxes[j];
                float area_j = (bj.z - bj.x) * (bj.w - bj.y);
                float xx1 = fmaxf(bi.x, bj.x), yy1 = fmaxf(bi.y, bj.y);
                float xx2 = fminf(bi.z, bj.z), yy2 = fminf(bi.w, bj.w);
                float iw = fmaxf(xx2 - xx1, 0.0f), ih = fmaxf(yy2 - yy1, 0.0f);
                float inter = iw * ih;
                float iou = inter / (area_i + area_j - inter + 1e-9f);
                sup = iou > 0.7f;
            }
            u64 m = __ballot(sup);
            if (lane == 0 && m) removed[c] |= m;   // one writer per word
        }
        __syncthreads();
        ++i;
    }
    __syncthreads();

    for (int r = tid; r < POST_NMS_N; r += 1024) {
        float4 v = make_float4(0.0f, 0.0f, 0.0f, 0.0f);
        if (r < kc) v = boxes[kept[r]];
        ((float4*)out)[r] = v;
    }
}

extern "C" void kernel_launch(void* const* d_in, const int* in_sizes, int n_in,
                              void* d_out, int out_size, void* d_ws, size_t ws_size,
                              hipStream_t stream) {
    const float4* anchors = (const float4*)d_in[0];
    const float*  cls     = (const float*)d_in[1];
    const float4* reg     = (const float4*)d_in[2];
    const int*    img_w   = (const int*)d_in[3];
    const int*    img_h   = (const int*)d_in[4];

    char* ws = (char*)d_ws;
    float4* bbox   = (float4*)(ws + 0);
    u64*    keys   = (u64*)   (ws + 589824);
    u64*    ckeys  = (u64*)   (ws + 884736);
    float4* sboxes = (float4*)(ws + 950272);
    u32*    meta   = (u32*)   (ws + 1046272);

    k_decode <<<dim3((N_ANCH + 255) / 256), dim3(256), 0, stream>>>(
        anchors, cls, reg, img_w, img_h, bbox, keys, ckeys, meta);
    k_select <<<dim3(1), dim3(1024), 0, stream>>>(keys, meta);
    k_compact<<<dim3((N_ANCH + 255) / 256), dim3(256), 0, stream>>>(keys, ckeys, meta);
    k_sort   <<<dim3(1), dim3(1024), 0, stream>>>(ckeys, bbox, sboxes);
    k_nms    <<<dim3(1), dim3(1024), 0, stream>>>(sboxes, (float*)d_out);
}

// Round 2
// 236.452 us; speedup vs baseline: 2.9235x; 2.9235x over previous
//
#include <hip/hip_runtime.h>
#include <stdint.h>

typedef unsigned long long u64;
typedef unsigned int u32;

#define N_ANCH     36864
#define PRE_NMS_N  6000
#define POST_NMS_N 300
#define NBINS      8192
#define CAP        8192     // compacted-candidate capacity (power of 2 for bitonic)
#define NWORDS     94       // ceil(6000/64)

// ---- workspace layout (bytes) ----
// 0        : float4 bbox[36864]     589824
// 589824   : u64    keys[36864]     294912
// 884736   : u64    ckeys[8192]      65536
// 950272   : float4 sboxes[6000]     96000
// 1046272  : u32    meta[8]             32
// 1046304  : u64    irem[94]           752   (init removed mask, from k_sort)
// 1047104  : u64    M[6000*94]     4512000   (suppression bitmask matrix)
#define OFF_BBOX   0
#define OFF_KEYS   589824
#define OFF_CKEYS  884736
#define OFF_SBOX   950272
#define OFF_META   1046272
#define OFF_IREM   1046304
#define OFF_M      1047104
#define WS_NEED    (OFF_M + (size_t)PRE_NMS_N * NWORDS * 8 + 1024)

__device__ __forceinline__ u64 make_key(float s, u32 idx) {
    u32 u = __float_as_uint(s);
    u32 sortable = u ^ ((u >> 31) ? 0xFFFFFFFFu : 0x80000000u);
    u32 hi = ~sortable;                 // ascending key == descending score
    return ((u64)hi << 32) | (u64)idx;  // tie-break: ascending index (stable argsort)
}

// K1: decode + clip + valid + key build; prefill ckeys pad; zero meta counter
__global__ void k_decode(const float4* __restrict__ anchors,
                         const float* __restrict__ cls,
                         const float4* __restrict__ reg,
                         const int* __restrict__ img_w,
                         const int* __restrict__ img_h,
                         float4* __restrict__ bbox,
                         u64* __restrict__ keys,
                         u64* __restrict__ ckeys,
                         u32* __restrict__ meta) {
    int i = blockIdx.x * blockDim.x + threadIdx.x;
    if (i == 0) meta[0] = 0u;
    if (i < CAP) ckeys[i] = ~0ull;      // pad for bitonic sort
    if (i >= N_ANCH) return;

    float4 a = anchors[i];
    float4 r = reg[i];
    float w  = a.z - a.x, h = a.w - a.y;
    float cx = a.x + 0.5f * w, cy = a.y + 0.5f * h;
    float pcx = r.x * w + cx, pcy = r.y * h + cy;
    float pw = expf(r.z) * w,  ph = expf(r.w) * h;
    float b0 = pcx - 0.5f * pw, b1 = pcy - 0.5f * ph;
    float b2 = pcx + 0.5f * pw, b3 = pcy + 0.5f * ph;

    float fh = (float)img_h[0], fw = (float)img_w[0];
    // reference: cols 0,2 clipped to [0, img_h]; cols 1,3 to [0, img_w]
    b0 = fminf(fmaxf(b0, 0.0f), fh);
    b2 = fminf(fmaxf(b2, 0.0f), fh);
    b1 = fminf(fmaxf(b1, 0.0f), fw);
    b3 = fminf(fmaxf(b3, 0.0f), fw);

    bool valid = (b2 - b0 >= 16.0f) && (b3 - b1 >= 16.0f);
    float score = valid ? cls[i] : -1e9f;

    bbox[i] = make_float4(b0, b1, b2, b3);
    keys[i] = make_key(score, (u32)i);
}

// K2: 13-bit-prefix histogram; find boundary bin B (count(bin<B) < 6000 <= count(bin<=B))
__global__ void k_select(const u64* __restrict__ keys, u32* __restrict__ meta) {
    __shared__ u32 hist[NBINS];
    __shared__ u32 psum[1024];
    int tid = threadIdx.x;
    for (int b = tid; b < NBINS; b += 1024) hist[b] = 0u;
    __syncthreads();
    for (int i = tid; i < N_ANCH; i += 1024)
        atomicAdd(&hist[(u32)(keys[i] >> 51)], 1u);
    __syncthreads();
    u32 s = 0;
    int base = tid * 8;
#pragma unroll
    for (int b = 0; b < 8; ++b) s += hist[base + b];
    psum[tid] = s;
    __syncthreads();
    for (int off = 1; off < 1024; off <<= 1) {
        u32 v = (tid >= off) ? psum[tid - off] : 0u;
        __syncthreads();
        psum[tid] += v;
        __syncthreads();
    }
    u32 incl = psum[tid];
    u32 excl = incl - s;
    if (excl < (u32)PRE_NMS_N && incl >= (u32)PRE_NMS_N) {
        u32 c = excl;
        for (int b = 0; b < 8; ++b) {
            u32 hv = hist[base + b];
            if (c + hv >= (u32)PRE_NMS_N) { meta[1] = (u32)(base + b); meta[2] = c; break; }
            c += hv;
        }
    }
}

// K3: compact keys with bin <= B into ckeys (unordered; sort fixes order)
__global__ void k_compact(const u64* __restrict__ keys,
                          u64* __restrict__ ckeys,
                          u32* __restrict__ meta) {
    int i = blockIdx.x * blockDim.x + threadIdx.x;
    if (i >= N_ANCH) return;
    u32 B = meta[1];
    u64 k = keys[i];
    if ((u32)(k >> 51) <= B) {
        u32 pos = atomicAdd(&meta[0], 1u);
        if (pos < CAP) ckeys[pos] = k;
    }
}

// K4: single-workgroup bitonic sort of 8192 keys in LDS; gather top-6000 boxes;
// emit initial removed-mask words (invalid boxes + pad bits)
__global__ void k_sort(const u64* __restrict__ ckeys,
                       const float4* __restrict__ bbox,
                       float4* __restrict__ sboxes,
                       u64* __restrict__ irem) {
    __shared__ u64 sk[CAP];   // 64 KiB
    int tid = threadIdx.x;
    for (int i = tid; i < CAP; i += 1024) sk[i] = ckeys[i];
    __syncthreads();
    for (int k = 2; k <= CAP; k <<= 1) {
        for (int j = k >> 1; j > 0; j >>= 1) {
            for (int idx = tid; idx < CAP; idx += 1024) {
                int p = idx ^ j;
                if (p > idx) {
                    u64 A = sk[idx], B = sk[p];
                    bool up = ((idx & k) == 0);
                    if ((A > B) == up) { sk[idx] = B; sk[p] = A; }
                }
            }
            __syncthreads();
        }
    }
    for (int r = tid; r < NWORDS * 64; r += 1024) {
        bool rm = true;
        if (r < PRE_NMS_N) {
            u32 idx = (u32)sk[r];
            float4 b = bbox[idx];
            sboxes[r] = b;
            rm = !((b.z - b.x >= 16.0f) && (b.w - b.y >= 16.0f));
        }
        u64 m = __ballot(rm);
        if ((tid & 63) == 0) irem[r >> 6] = m;
    }
}

// K5a: suppression bitmask matrix. Block = 16 waves; wave w computes row
// i = blockIdx*16+w against all 6000 boxes staged in LDS.
__global__ __launch_bounds__(1024) void k_iou(const float4* __restrict__ sboxes,
                                              u64* __restrict__ M) {
    __shared__ float4 sb[PRE_NMS_N];   // 96000 B
    int tid = threadIdx.x, lane = tid & 63, wave = tid >> 6;
    for (int r = tid; r < PRE_NMS_N; r += 1024) sb[r] = sboxes[r];
    __syncthreads();

    int i = blockIdx.x * 16 + wave;    // grid = 375 -> i in [0,6000)
    float4 bi = sb[i];
    float ai = (bi.z - bi.x) * (bi.w - bi.y);
    int w0 = i >> 6;
    u64* row = M + (size_t)i * NWORDS;
    for (int w = 0; w < NWORDS; ++w) {
        u64 m = 0;
        if (w >= w0) {
            int j = (w << 6) + lane;
            bool sup = false;
            if (j > i && j < PRE_NMS_N) {
                float4 bj = sb[j];
                float aj = (bj.z - bj.x) * (bj.w - bj.y);
                float xx1 = fmaxf(bi.x, bj.x), yy1 = fmaxf(bi.y, bj.y);
                float xx2 = fminf(bi.z, bj.z), yy2 = fminf(bi.w, bj.w);
                float inter = fmaxf(xx2 - xx1, 0.0f) * fmaxf(yy2 - yy1, 0.0f);
                float iou = inter / (ai + aj - inter + 1e-9f);  // keep EXACT ref arithmetic
                sup = iou > 0.7f;
            }
            m = __ballot(sup);
        }
        if (lane == 0) row[w] = m;
    }
}

// K5b: single-wave serial greedy reduce over precomputed rows.
// removed mask lives in 2 u64 registers per lane (94 words across 64 lanes).
__global__ __launch_bounds__(64) void k_reduce(const float4* __restrict__ sboxes,
                                               const u64* __restrict__ M,
                                               const u64* __restrict__ irem,
                                               float* __restrict__ out) {
    __shared__ int kept[POST_NMS_N];
    int lane = threadIdx.x;
    u64 rem0 = irem[lane];
    u64 rem1 = (lane < NWORDS - 64) ? irem[64 + lane] : ~0ull;
    int w1idx = (lane < NWORDS - 64) ? (64 + lane) : (NWORDS - 1);  // clamped in-row word
    int kc = 0;
    bool done = false;

    u64 a0[8], a1[8], b0[8], b1[8];

#define LOAD_BATCH(R0, R1, BASE)                                       \
    {                                                                  \
        _Pragma("unroll")                                              \
        for (int t = 0; t < 8; ++t) {                                  \
            int q = (BASE) + t;                                        \
            q = q < PRE_NMS_N ? q : (PRE_NMS_N - 1);                   \
            const u64* rp = M + (size_t)q * NWORDS;                    \
            R0[t] = rp[lane];                                          \
            R1[t] = rp[w1idx];                                         \
        }                                                              \
    }

#define PROC_BATCH(R0, R1, BASE)                                       \
    {                                                                  \
        _Pragma("unroll")                                              \
        for (int t = 0; t < 8; ++t) {                                  \
            int q = (BASE) + t;                                        \
            if (!done && q < PRE_NMS_N) {                              \
                int owner = q >> 6;                                    \
                u64 wsel = (owner < 64) ? __shfl(rem0, owner)          \
                                        : __shfl(rem1, owner - 64);    \
                if (!((wsel >> (q & 63)) & 1ull)) {                    \
                    if (lane == 0) kept[kc] = q;                       \
                    ++kc;                                              \
                    rem0 |= R0[t];                                     \
                    rem1 |= R1[t];                                     \
                    if (kc >= POST_NMS_N) done = true;                 \
                }                                                      \
            }                                                          \
        }                                                              \
    }

    LOAD_BATCH(a0, a1, 0);
    for (int base = 0; base < PRE_NMS_N; base += 16) {
        LOAD_BATCH(b0, b1, base + 8);
        PROC_BATCH(a0, a1, base);
        if (done) break;
        LOAD_BATCH(a0, a1, base + 16);
        PROC_BATCH(b0, b1, base + 8);
        if (done) break;
    }
#undef LOAD_BATCH
#undef PROC_BATCH

    // lane0 wrote kept[]; single wave => in-order LDS visibility, no barrier needed
    for (int r = lane; r < POST_NMS_N; r += 64) {
        float4 v = make_float4(0.0f, 0.0f, 0.0f, 0.0f);
        if (r < kc) v = sboxes[kept[r]];
        ((float4*)out)[r] = v;
    }
}

// Fallback NMS (R0 path) in case ws_size is too small for the bitmask matrix.
__global__ void k_nms(const float4* __restrict__ sboxes, float* __restrict__ out) {
    __shared__ float4 boxes[PRE_NMS_N];
    __shared__ u64 removed[NWORDS];
    __shared__ int kept[POST_NMS_N];
    int tid = threadIdx.x;
    int lane = tid & 63, wave = tid >> 6;

    for (int r = tid; r < PRE_NMS_N; r += 1024) boxes[r] = sboxes[r];
    __syncthreads();
    for (int r = tid; r < NWORDS * 64; r += 1024) {
        bool rm = true;
        if (r < PRE_NMS_N) {
            float4 b = boxes[r];
            rm = !((b.z - b.x >= 16.0f) && (b.w - b.y >= 16.0f));
        }
        u64 m = __ballot(rm);
        if (lane == 0) removed[r >> 6] = m;
    }
    __syncthreads();

    int kc = 0;
    int i = 0;
    while (i < PRE_NMS_N) {
        int w = i >> 6;
        u64 wd = removed[w] | ((1ull << (i & 63)) - 1ull);
        while (wd == ~0ull) {
            ++w;
            if (w >= NWORDS) break;
            wd = removed[w];
        }
        if (w >= NWORDS) break;
        i = (w << 6) + (__ffsll((u64)(~wd)) - 1);
        if (i >= PRE_NMS_N) break;

        if (tid == 0) kept[kc] = i;
        ++kc;
        if (kc >= POST_NMS_N) break;

        float4 bi = boxes[i];
        float area_i = (bi.z - bi.x) * (bi.w - bi.y);
        for (int c = (i >> 6) + wave; c < NWORDS; c += 16) {
            int j = (c << 6) + lane;
            bool sup = false;
            if (j > i && j < PRE_NMS_N) {
                float4 bj = boxes[j];
                float area_j = (bj.z - bj.x) * (bj.w - bj.y);
                float xx1 = fmaxf(bi.x, bj.x), yy1 = fmaxf(bi.y, bj.y);
                float xx2 = fminf(bi.z, bj.z), yy2 = fminf(bi.w, bj.w);
                float iw = fmaxf(xx2 - xx1, 0.0f), ih = fmaxf(yy2 - yy1, 0.0f);
                float inter = iw * ih;
                float iou = inter / (area_i + area_j - inter + 1e-9f);
                sup = iou > 0.7f;
            }
            u64 m = __ballot(sup);
            if (lane == 0 && m) removed[c] |= m;
        }
        __syncthreads();
        ++i;
    }
    __syncthreads();

    for (int r = tid; r < POST_NMS_N; r += 1024) {
        float4 v = make_float4(0.0f, 0.0f, 0.0f, 0.0f);
        if (r < kc) v = boxes[kept[r]];
        ((float4*)out)[r] = v;
    }
}

extern "C" void kernel_launch(void* const* d_in, const int* in_sizes, int n_in,
                              void* d_out, int out_size, void* d_ws, size_t ws_size,
                              hipStream_t stream) {
    const float4* anchors = (const float4*)d_in[0];
    const float*  cls     = (const float*)d_in[1];
    const float4* reg     = (const float4*)d_in[2];
    const int*    img_w   = (const int*)d_in[3];
    const int*    img_h   = (const int*)d_in[4];

    char* ws = (char*)d_ws;
    float4* bbox   = (float4*)(ws + OFF_BBOX);
    u64*    keys   = (u64*)   (ws + OFF_KEYS);
    u64*    ckeys  = (u64*)   (ws + OFF_CKEYS);
    float4* sboxes = (float4*)(ws + OFF_SBOX);
    u32*    meta   = (u32*)   (ws + OFF_META);
    u64*    irem   = (u64*)   (ws + OFF_IREM);
    u64*    M      = (u64*)   (ws + OFF_M);

    k_decode <<<dim3((N_ANCH + 255) / 256), dim3(256), 0, stream>>>(
        anchors, cls, reg, img_w, img_h, bbox, keys, ckeys, meta);
    k_select <<<dim3(1), dim3(1024), 0, stream>>>(keys, meta);
    k_compact<<<dim3((N_ANCH + 255) / 256), dim3(256), 0, stream>>>(keys, ckeys, meta);
    k_sort   <<<dim3(1), dim3(1024), 0, stream>>>(ckeys, bbox, sboxes, irem);

    if (ws_size >= WS_NEED) {
        k_iou    <<<dim3(PRE_NMS_N / 16), dim3(1024), 0, stream>>>(sboxes, M);
        k_reduce <<<dim3(1), dim3(64), 0, stream>>>(sboxes, M, irem, (float*)d_out);
    } else {
        k_nms    <<<dim3(1), dim3(1024), 0, stream>>>(sboxes, (float*)d_out);
    }
}